// Round 1
// baseline (1317.018 us; speedup 1.0000x reference)
//
#include <hip/hip_runtime.h>
#include <stdint.h>

#define N_TOK 8192
#define DDIM 2048
#define IDIM 6144
#define NEXP 8
#define RLORA 32

typedef __attribute__((ext_vector_type(8))) short short8;
typedef __attribute__((ext_vector_type(4))) float floatx4;
typedef __attribute__((ext_vector_type(4))) unsigned short ushortx4;

__device__ __forceinline__ unsigned short f2bf(float f) {
  union { float f; unsigned u; } v; v.f = f;
  unsigned u = v.u;
  unsigned r = (u + 0x7fffu + ((u >> 16) & 1u)) >> 16;
  return (unsigned short)r;
}
__device__ __forceinline__ float bf2f(unsigned short s) {
  union { unsigned u; float f; } v; v.u = ((unsigned)s) << 16;
  return v.f;
}

__device__ __forceinline__ void gload_lds16(const void* g, void* l) {
  __builtin_amdgcn_global_load_lds(
      (const __attribute__((address_space(1))) void*)g,
      (__attribute__((address_space(3))) void*)l, 16, 0, 0);
}

// ---------------- router + x->bf16 convert (one wave per token) ----------------
__global__ __launch_bounds__(256) void router_kernel(
    const float* __restrict__ x, const float* __restrict__ rw,
    unsigned short* __restrict__ xb, float* __restrict__ logits_out,
    int* __restrict__ idx) {
  int wave = threadIdx.x >> 6, lane = threadIdx.x & 63;
  int n = blockIdx.x * 4 + wave;
  const float* xr = x + (size_t)n * DDIM;
  unsigned short* xbr = xb + (size_t)n * DDIM;
  float acc[NEXP];
#pragma unroll
  for (int e = 0; e < NEXP; e++) acc[e] = 0.f;
#pragma unroll
  for (int j = 0; j < 8; j++) {
    int d = j * 256 + lane * 4;
    floatx4 v = *(const floatx4*)(xr + d);
    ushortx4 s;
    s[0] = f2bf(v[0]); s[1] = f2bf(v[1]); s[2] = f2bf(v[2]); s[3] = f2bf(v[3]);
    *(ushortx4*)(xbr + d) = s;
    const float* rwd = rw + (size_t)d * NEXP;
#pragma unroll
    for (int t = 0; t < 4; t++) {
      float xv = v[t];
      const float* rr = rwd + t * NEXP;
#pragma unroll
      for (int e = 0; e < NEXP; e++) acc[e] += xv * rr[e];
    }
  }
#pragma unroll
  for (int off = 32; off > 0; off >>= 1) {
#pragma unroll
    for (int e = 0; e < NEXP; e++) acc[e] += __shfl_xor(acc[e], off, 64);
  }
  if (lane == 0) {
    float best = acc[0]; int bi = 0;
#pragma unroll
    for (int e = 1; e < NEXP; e++)
      if (acc[e] > best) { best = acc[e]; bi = e; }
    idx[n] = bi;
#pragma unroll
    for (int e = 0; e < NEXP; e++) logits_out[(size_t)n * NEXP + e] = acc[e];
  }
}

// ---------------- fp32 [Rr][Cc] -> bf16 [Cc][Rr] transpose ----------------
__global__ __launch_bounds__(256) void transpose_w_kernel(
    const float* __restrict__ in, unsigned short* __restrict__ out, int Rr, int Cc) {
  __shared__ float lds[32][33];
  int r0 = blockIdx.y * 32, c0 = blockIdx.x * 32;
  int tx = threadIdx.x & 31, ty = threadIdx.x >> 5;
#pragma unroll
  for (int k = 0; k < 4; k++) {
    int r = ty + k * 8;
    lds[r][tx] = in[(size_t)(r0 + r) * Cc + c0 + tx];
  }
  __syncthreads();
#pragma unroll
  for (int k = 0; k < 4; k++) {
    int cc = ty + k * 8;
    out[(size_t)(c0 + cc) * Rr + r0 + tx] = f2bf(lds[tx][cc]);
  }
}

// ---------------- pack A_gate/A_up -> aat[512][2048] bf16 (col = h*256+e*32+r) ----------------
__global__ __launch_bounds__(256) void pack_a_kernel(
    const float* __restrict__ Ag, const float* __restrict__ Au,
    unsigned short* __restrict__ aat) {
  int o = blockIdx.x * 256 + threadIdx.x;    // [0, 2^20)
  int h = o >> 19;
  int oo = o & ((1 << 19) - 1);
  int c = oo >> 11, d = oo & 2047;           // c in [0,256)
  int e = c >> 5, r = c & 31;
  const float* src = h ? Au : Ag;
  float v = src[(e << 16) + (d << 5) + r];   // A[e][d][r]
  aat[(size_t)(h * 256 + c) * DDIM + d] = f2bf(v);
}

// ---------------- B[e][R][I] fp32 -> Bt[e][I][R] bf16 ----------------
__global__ __launch_bounds__(256) void transpose_b_kernel(
    const float* __restrict__ Bg, const float* __restrict__ Bu,
    unsigned short* __restrict__ btg, unsigned short* __restrict__ btu) {
  __shared__ float lds[32][33];
  int i0 = blockIdx.x * 32, e = blockIdx.y;
  const float* in = blockIdx.z ? Bu : Bg;
  unsigned short* out = blockIdx.z ? btu : btg;
  int tx = threadIdx.x & 31, ty = threadIdx.x >> 5;
#pragma unroll
  for (int k = 0; k < 4; k++) {
    int r = ty + k * 8;
    lds[r][tx] = in[((size_t)e * RLORA + r) * IDIM + i0 + tx];
  }
  __syncthreads();
#pragma unroll
  for (int k = 0; k < 4; k++) {
    int ii = ty + k * 8;
    out[((size_t)e * IDIM + i0 + ii) * RLORA + tx] = f2bf(lds[tx][ii]);
  }
}

// ---------------- shared GEMM main loop: C[128x128] += A[128xK] * B^T[128xK] ----------------
// A row-major [rows][K], B stored as [cols][K] (K-contiguous). BK=32, 4 waves 2x2.
__device__ __forceinline__ void mm_main(const unsigned short* __restrict__ Ab,
                                        const unsigned short* __restrict__ Bb,
                                        int K, int row0, int col0,
                                        unsigned short* sA, unsigned short* sB,
                                        floatx4* acc) {
  const int tid = threadIdx.x;
  const int wave = tid >> 6, lane = tid & 63;
  const int wr = wave >> 1, wc = wave & 1;
  const int q = lane >> 4, m16 = lane & 15;
  for (int k0 = 0; k0 < K; k0 += 32) {
    __syncthreads();
#pragma unroll
    for (int rr = 0; rr < 2; rr++) {
      int e = tid * 8 + rr * 2048;
      int r = e >> 5, kk = e & 31;
      gload_lds16(Ab + (size_t)(row0 + r) * K + (k0 + kk), sA + e);
      gload_lds16(Bb + (size_t)(col0 + r) * K + (k0 + kk), sB + e);
    }
    __syncthreads();
    short8 a[4], b[4];
#pragma unroll
    for (int m = 0; m < 4; m++)
      a[m] = *(const short8*)(sA + (wr * 64 + m * 16 + m16) * 32 + q * 8);
#pragma unroll
    for (int n = 0; n < 4; n++)
      b[n] = *(const short8*)(sB + (wc * 64 + n * 16 + m16) * 32 + q * 8);
#pragma unroll
    for (int m = 0; m < 4; m++)
#pragma unroll
      for (int n = 0; n < 4; n++)
        acc[m * 4 + n] = __builtin_amdgcn_mfma_f32_16x16x32_bf16(a[m], b[n], acc[m * 4 + n], 0, 0, 0);
  }
}

// ---------------- LoRA epilogue: acc += mask_e(t) @ B_e, 8 experts ----------------
__device__ __forceinline__ void lora_epilogue(const unsigned short* __restrict__ Tm,
                                              const unsigned short* __restrict__ Bt,
                                              const int* __restrict__ idx,
                                              int half, int row0, int col0,
                                              unsigned short* sA, unsigned short* sB,
                                              int* es_s, floatx4* acc) {
  const int tid = threadIdx.x;
  const int wave = tid >> 6, lane = tid & 63;
  const int wr = wave >> 1, wc = wave & 1;
  const int q = lane >> 4, m16 = lane & 15;
  __syncthreads();
  if (tid < 128) es_s[tid] = idx[row0 + tid];
#pragma unroll
  for (int rr = 0; rr < 2; rr++) {
    int e = tid * 8 + rr * 2048;
    int r = e >> 5, kk = e & 31;
    int ex = idx[row0 + r];
    const unsigned short* src = Tm + (size_t)(row0 + r) * 512 + half * 256 + ex * 32 + kk;
    *(floatx4*)(sA + e) = *(const floatx4*)src;
  }
  __syncthreads();
  short8 ta[4]; int erow[4];
#pragma unroll
  for (int m = 0; m < 4; m++) {
    int rloc = wr * 64 + m * 16 + m16;
    ta[m] = *(const short8*)(sA + rloc * 32 + q * 8);
    erow[m] = es_s[rloc];
  }
  short8 zero;
#pragma unroll
  for (int i = 0; i < 8; i++) zero[i] = 0;
  for (int ee = 0; ee < NEXP; ee++) {
    __syncthreads();
#pragma unroll
    for (int rr = 0; rr < 2; rr++) {
      int e2 = tid * 8 + rr * 2048;
      int c = e2 >> 5, kk = e2 & 31;
      *(floatx4*)(sB + e2) = *(const floatx4*)(Bt + ((size_t)ee * IDIM + col0 + c) * RLORA + kk);
    }
    __syncthreads();
    short8 bfr[4];
#pragma unroll
    for (int n = 0; n < 4; n++)
      bfr[n] = *(const short8*)(sB + (wc * 64 + n * 16 + m16) * 32 + q * 8);
#pragma unroll
    for (int m = 0; m < 4; m++) {
      short8 am = (erow[m] == ee) ? ta[m] : zero;
#pragma unroll
      for (int n = 0; n < 4; n++)
        acc[m * 4 + n] = __builtin_amdgcn_mfma_f32_16x16x32_bf16(am, bfr[n], acc[m * 4 + n], 0, 0, 0);
    }
  }
}

// ---------------- GEMM kernels ----------------
__global__ __launch_bounds__(256) void gemm_t_kernel(
    const unsigned short* __restrict__ xb, const unsigned short* __restrict__ aat,
    unsigned short* __restrict__ Tm) {
  __shared__ __align__(16) unsigned short sA[4096], sB[4096];
  floatx4 acc[16];
#pragma unroll
  for (int i = 0; i < 16; i++)
#pragma unroll
    for (int j = 0; j < 4; j++) acc[i][j] = 0.f;
  int row0 = blockIdx.y * 128, col0 = blockIdx.x * 128;
  mm_main(xb, aat, DDIM, row0, col0, sA, sB, acc);
  const int wave = threadIdx.x >> 6, lane = threadIdx.x & 63;
  const int wr = wave >> 1, wc = wave & 1;
  const int q = lane >> 4, m16 = lane & 15;
#pragma unroll
  for (int m = 0; m < 4; m++)
#pragma unroll
    for (int n = 0; n < 4; n++)
#pragma unroll
      for (int r = 0; r < 4; r++) {
        int grow = row0 + wr * 64 + m * 16 + q * 4 + r;
        int gcol = col0 + wc * 64 + n * 16 + m16;
        Tm[(size_t)grow * 512 + gcol] = f2bf(acc[m * 4 + n][r]);
      }
}

__global__ __launch_bounds__(256) void gemm_gate_kernel(
    const unsigned short* __restrict__ xb, const unsigned short* __restrict__ wgt,
    const unsigned short* __restrict__ Tm, const unsigned short* __restrict__ btg,
    const int* __restrict__ idx, unsigned short* __restrict__ gbuf) {
  __shared__ __align__(16) unsigned short sA[4096], sB[4096];
  __shared__ int es_s[128];
  floatx4 acc[16];
#pragma unroll
  for (int i = 0; i < 16; i++)
#pragma unroll
    for (int j = 0; j < 4; j++) acc[i][j] = 0.f;
  int row0 = blockIdx.y * 128, col0 = blockIdx.x * 128;
  mm_main(xb, wgt, DDIM, row0, col0, sA, sB, acc);
  lora_epilogue(Tm, btg, idx, 0, row0, col0, sA, sB, es_s, acc);
  const int wave = threadIdx.x >> 6, lane = threadIdx.x & 63;
  const int wr = wave >> 1, wc = wave & 1;
  const int q = lane >> 4, m16 = lane & 15;
#pragma unroll
  for (int m = 0; m < 4; m++)
#pragma unroll
    for (int n = 0; n < 4; n++)
#pragma unroll
      for (int r = 0; r < 4; r++) {
        int grow = row0 + wr * 64 + m * 16 + q * 4 + r;
        int gcol = col0 + wc * 64 + n * 16 + m16;
        gbuf[(size_t)grow * IDIM + gcol] = f2bf(acc[m * 4 + n][r]);
      }
}

__global__ __launch_bounds__(256) void gemm_up_kernel(
    const unsigned short* __restrict__ xb, const unsigned short* __restrict__ wut,
    const unsigned short* __restrict__ Tm, const unsigned short* __restrict__ btu,
    const int* __restrict__ idx, unsigned short* __restrict__ gbuf) {
  __shared__ __align__(16) unsigned short sA[4096], sB[4096];
  __shared__ int es_s[128];
  floatx4 acc[16];
#pragma unroll
  for (int i = 0; i < 16; i++)
#pragma unroll
    for (int j = 0; j < 4; j++) acc[i][j] = 0.f;
  int row0 = blockIdx.y * 128, col0 = blockIdx.x * 128;
  mm_main(xb, wut, DDIM, row0, col0, sA, sB, acc);
  lora_epilogue(Tm, btu, idx, 1, row0, col0, sA, sB, es_s, acc);
  const int wave = threadIdx.x >> 6, lane = threadIdx.x & 63;
  const int wr = wave >> 1, wc = wave & 1;
  const int q = lane >> 4, m16 = lane & 15;
#pragma unroll
  for (int m = 0; m < 4; m++)
#pragma unroll
    for (int n = 0; n < 4; n++)
#pragma unroll
      for (int r = 0; r < 4; r++) {
        int grow = row0 + wr * 64 + m * 16 + q * 4 + r;
        int gcol = col0 + wc * 64 + n * 16 + m16;
        size_t o = (size_t)grow * IDIM + gcol;
        float gv = bf2f(gbuf[o]);
        float hv = gv / (1.f + __expf(-gv)) * acc[m * 4 + n][r];
        gbuf[o] = f2bf(hv);   // h overwrites g in place
      }
}

__global__ __launch_bounds__(256) void gemm_down_kernel(
    const unsigned short* __restrict__ hb, const unsigned short* __restrict__ wdt,
    float* __restrict__ out) {
  __shared__ __align__(16) unsigned short sA[4096], sB[4096];
  floatx4 acc[16];
#pragma unroll
  for (int i = 0; i < 16; i++)
#pragma unroll
    for (int j = 0; j < 4; j++) acc[i][j] = 0.f;
  int row0 = blockIdx.y * 128, col0 = blockIdx.x * 128;
  mm_main(hb, wdt, IDIM, row0, col0, sA, sB, acc);
  const int wave = threadIdx.x >> 6, lane = threadIdx.x & 63;
  const int wr = wave >> 1, wc = wave & 1;
  const int q = lane >> 4, m16 = lane & 15;
#pragma unroll
  for (int m = 0; m < 4; m++)
#pragma unroll
    for (int n = 0; n < 4; n++)
#pragma unroll
      for (int r = 0; r < 4; r++) {
        int grow = row0 + wr * 64 + m * 16 + q * 4 + r;
        int gcol = col0 + wc * 64 + n * 16 + m16;
        out[(size_t)grow * DDIM + gcol] = acc[m * 4 + n][r];
      }
}

extern "C" void kernel_launch(void* const* d_in, const int* in_sizes, int n_in,
                              void* d_out, int out_size, void* d_ws, size_t ws_size,
                              hipStream_t stream) {
  const float* x  = (const float*)d_in[0];
  const float* rw = (const float*)d_in[1];
  const float* Ag = (const float*)d_in[2];
  const float* Bg = (const float*)d_in[3];
  const float* Au = (const float*)d_in[4];
  const float* Bu = (const float*)d_in[5];
  const float* Wg = (const float*)d_in[6];
  const float* Wu = (const float*)d_in[7];
  const float* Wd = (const float*)d_in[8];
  float* out = (float*)d_out;
  float* logits = out + (size_t)N_TOK * DDIM;

  char* ws = (char*)d_ws;
  size_t off = 0;
  auto alloc = [&](size_t bytes) {
    char* p = ws + off;
    off += (bytes + 255) & ~(size_t)255;
    return p;
  };
  unsigned short* xb  = (unsigned short*)alloc((size_t)N_TOK * DDIM * 2);
  unsigned short* wgt = (unsigned short*)alloc((size_t)IDIM * DDIM * 2);
  unsigned short* wut = (unsigned short*)alloc((size_t)IDIM * DDIM * 2);
  unsigned short* wdt = (unsigned short*)alloc((size_t)DDIM * IDIM * 2);
  unsigned short* aat = (unsigned short*)alloc((size_t)512 * DDIM * 2);
  unsigned short* btg = (unsigned short*)alloc((size_t)NEXP * IDIM * RLORA * 2);
  unsigned short* btu = (unsigned short*)alloc((size_t)NEXP * IDIM * RLORA * 2);
  unsigned short* Tm  = (unsigned short*)alloc((size_t)N_TOK * 512 * 2);
  unsigned short* gbuf= (unsigned short*)alloc((size_t)N_TOK * IDIM * 2);
  int* idx = (int*)alloc((size_t)N_TOK * 4);

  router_kernel<<<N_TOK / 4, 256, 0, stream>>>(x, rw, xb, logits, idx);
  transpose_w_kernel<<<dim3(IDIM / 32, DDIM / 32), 256, 0, stream>>>(Wg, wgt, DDIM, IDIM);
  transpose_w_kernel<<<dim3(IDIM / 32, DDIM / 32), 256, 0, stream>>>(Wu, wut, DDIM, IDIM);
  transpose_w_kernel<<<dim3(DDIM / 32, IDIM / 32), 256, 0, stream>>>(Wd, wdt, IDIM, DDIM);
  pack_a_kernel<<<4096, 256, 0, stream>>>(Ag, Au, aat);
  transpose_b_kernel<<<dim3(IDIM / 32, NEXP, 2), 256, 0, stream>>>(Bg, Bu, btg, btu);
  gemm_t_kernel<<<dim3(4, N_TOK / 128), 256, 0, stream>>>(xb, aat, Tm);
  gemm_gate_kernel<<<dim3(IDIM / 128, N_TOK / 128), 256, 0, stream>>>(xb, wgt, Tm, btg, idx, gbuf);
  gemm_up_kernel<<<dim3(IDIM / 128, N_TOK / 128), 256, 0, stream>>>(xb, wut, Tm, btu, idx, gbuf);
  gemm_down_kernel<<<dim3(DDIM / 128, N_TOK / 128), 256, 0, stream>>>(gbuf, wdt, out);
}